// Round 1
// baseline (2006.411 us; speedup 1.0000x reference)
//
#include <hip/hip_runtime.h>
#include <hip/hip_bf16.h>

#define NEG_SLOPE 0.2f

static inline int cdiv(int a, int b) { return (a + b - 1) / b; }

// ---------------- GEMM: C[N,M] = A[N,K] @ B[K,M], f32, 64x64 tile ----------------
__global__ __launch_bounds__(256) void gemm_f32(const float* __restrict__ A,
                                                const float* __restrict__ B,
                                                float* __restrict__ C,
                                                int N, int K, int M) {
  __shared__ float As[16][68];   // [k][row], pad 68 keeps 16B alignment (272B stride)
  __shared__ float Bs[16][64];   // [k][col]
  const int tid = threadIdx.x;
  const int row0 = blockIdx.x * 64;
  const int col0 = blockIdx.y * 64;
  const int tx = tid & 15, ty = tid >> 4;
  float acc[4][4] = {};
  for (int k0 = 0; k0 < K; k0 += 16) {
    {
      const int r = tid >> 2, kv = (tid & 3) << 2;
      const int row = row0 + r;
      float4 v = make_float4(0.f, 0.f, 0.f, 0.f);
      if (row < N) v = *reinterpret_cast<const float4*>(&A[(size_t)row * K + k0 + kv]);
      As[kv + 0][r] = v.x; As[kv + 1][r] = v.y; As[kv + 2][r] = v.z; As[kv + 3][r] = v.w;
    }
    {
      const int kr = tid >> 4, cv = (tid & 15) << 2;
      float4 v = *reinterpret_cast<const float4*>(&B[(size_t)(k0 + kr) * M + col0 + cv]);
      *reinterpret_cast<float4*>(&Bs[kr][cv]) = v;
    }
    __syncthreads();
#pragma unroll
    for (int kk = 0; kk < 16; ++kk) {
      float4 av = *reinterpret_cast<const float4*>(&As[kk][ty << 2]);
      float4 bv = *reinterpret_cast<const float4*>(&Bs[kk][tx << 2]);
      const float a[4] = {av.x, av.y, av.z, av.w};
      const float b[4] = {bv.x, bv.y, bv.z, bv.w};
#pragma unroll
      for (int i = 0; i < 4; ++i)
#pragma unroll
        for (int j = 0; j < 4; ++j)
          acc[i][j] = fmaf(a[i], b[j], acc[i][j]);
    }
    __syncthreads();
  }
#pragma unroll
  for (int i = 0; i < 4; ++i) {
    const int row = row0 + (ty << 2) + i;
    if (row < N) {
      float4 v = make_float4(acc[i][0], acc[i][1], acc[i][2], acc[i][3]);
      *reinterpret_cast<float4*>(&C[(size_t)row * M + col0 + (tx << 2)]) = v;
    }
  }
}

// ---------------- per-node attention scores: el/er[N,H] (F==64) ----------------
template <int H>
__global__ void scores_kernel(const float* __restrict__ feat,
                              const float* __restrict__ al,
                              const float* __restrict__ ar,
                              float* __restrict__ el, float* __restrict__ er, int N) {
  const int wid = (int)((blockIdx.x * (size_t)blockDim.x + threadIdx.x) >> 6);
  const int lane = threadIdx.x & 63;
  if (wid >= N) return;
#pragma unroll
  for (int h = 0; h < H; ++h) {
    float v = feat[(size_t)wid * (H * 64) + h * 64 + lane];
    float sl = v * al[h * 64 + lane];
    float sr = v * ar[h * 64 + lane];
#pragma unroll
    for (int off = 32; off; off >>= 1) {
      sl += __shfl_xor(sl, off);
      sr += __shfl_xor(sr, off);
    }
    if (lane == 0) { el[wid * H + h] = sl; er[wid * H + h] = sr; }
  }
}

// ---------------- init m (mapped-uint 0 == -inf) and s (0) ----------------
__global__ void init_ms(unsigned* __restrict__ mu, float* __restrict__ s, int n) {
  int i = blockIdx.x * blockDim.x + threadIdx.x;
  if (i < n) { mu[i] = 0u; s[i] = 0.f; }
}

// ---------------- edge logits + leaky relu + segment max ----------------
template <int H>
__global__ void edge_logits(const int* __restrict__ src, const int* __restrict__ dst,
                            const float* __restrict__ el, const float* __restrict__ er,
                            float* __restrict__ ebuf, unsigned* __restrict__ mu, int E) {
  int i = blockIdx.x * blockDim.x + threadIdx.x;
  if (i >= E * H) return;
  int e = i / H, h = i - e * H;
  int sn = src[e], dn = dst[e];
  float v = el[sn * H + h] + er[dn * H + h];
  v = v > 0.f ? v : NEG_SLOPE * v;
  ebuf[i] = v;
  unsigned b = __float_as_uint(v);
  unsigned key = b ^ ((b & 0x80000000u) ? 0xFFFFFFFFu : 0x80000000u);
  atomicMax(&mu[dn * H + h], key);
}

// ---------------- a = exp(e - m[dst]); s[dst] += a ----------------
template <int H>
__global__ void edge_exp(const int* __restrict__ dst, float* __restrict__ ebuf,
                         const unsigned* __restrict__ mu, float* __restrict__ ssum, int E) {
  int i = blockIdx.x * blockDim.x + threadIdx.x;
  if (i >= E * H) return;
  int e = i / H, h = i - e * H;
  int dn = dst[e];
  unsigned key = mu[dn * H + h];
  unsigned bits = (key & 0x80000000u) ? (key ^ 0x80000000u) : ~key;
  float m = __uint_as_float(bits);
  float a = expf(ebuf[i] - m);
  ebuf[i] = a;
  atomicAdd(&ssum[dn * H + h], a);
}

// ---------------- out[n,:] = b[:] ----------------
__global__ void init_out(float* __restrict__ out, const float* __restrict__ b, int total, int mmask) {
  int i = blockIdx.x * blockDim.x + threadIdx.x;
  if (i < total) out[i] = b[i & mmask];
}

// ---------------- out[dst] += feat[src] * alpha  (one wave per edge, F==64) ----------------
template <int H>
__global__ void aggregate(const int* __restrict__ src, const int* __restrict__ dst,
                          const float* __restrict__ feat, const float* __restrict__ abuf,
                          const float* __restrict__ ssum, float* __restrict__ out, int E) {
  const int wid = (int)((blockIdx.x * (size_t)blockDim.x + threadIdx.x) >> 6);
  const int lane = threadIdx.x & 63;
  if (wid >= E) return;
  const int sn = src[wid], dn = dst[wid];
#pragma unroll
  for (int h = 0; h < H; ++h) {
    float a = abuf[wid * H + h];
    float sd = ssum[dn * H + h];
    float w = a / fmaxf(sd, 1e-9f);
    float v = feat[(size_t)sn * (H * 64) + h * 64 + lane];
    atomicAdd(&out[(size_t)dn * (H * 64) + h * 64 + lane], v * w);
  }
}

// ---------------- tail: ids as float ----------------
__global__ void copy_ids(const int* __restrict__ ids, float* __restrict__ out, int n) {
  int i = blockIdx.x * blockDim.x + threadIdx.x;
  if (i < n) out[i] = (float)ids[i];
}

extern "C" void kernel_launch(void* const* d_in, const int* in_sizes, int n_in,
                              void* d_out, int out_size, void* d_ws, size_t ws_size,
                              hipStream_t stream) {
  const float* h   = (const float*)d_in[0];
  const int* src   = (const int*)d_in[1];
  const int* dst   = (const int*)d_in[2];
  const int* ids   = (const int*)d_in[3];
  const float* W0  = (const float*)d_in[4];
  const float* al0 = (const float*)d_in[5];
  const float* ar0 = (const float*)d_in[6];
  const float* b0  = (const float*)d_in[7];
  const float* W1  = (const float*)d_in[8];
  const float* al1 = (const float*)d_in[9];
  const float* ar1 = (const float*)d_in[10];
  const float* b1  = (const float*)d_in[11];
  const float* W2  = (const float*)d_in[12];
  const float* al2 = (const float*)d_in[13];
  const float* ar2 = (const float*)d_in[14];
  const float* b2  = (const float*)d_in[15];

  const int Din = 256, HF = 256, F2 = 64;
  const int N = in_sizes[0] / Din;        // 50000
  const int E = in_sizes[1];              // 800000
  const int NIDS = in_sizes[3];           // 1024

  // workspace layout (floats)
  float* feat = (float*)d_ws;                       // N*256
  float* hbuf = feat + (size_t)N * 256;             // N*256
  float* el   = hbuf + (size_t)N * 256;             // N*4
  float* er   = el + (size_t)N * 4;                 // N*4
  float* ebuf = er + (size_t)N * 4;                 // E*4
  unsigned* mu = (unsigned*)(ebuf + (size_t)E * 4); // N*4
  float* ssum = (float*)(mu + (size_t)N * 4);       // N*4

  float* outp = (float*)d_out;

  dim3 blk(256);

  // ---------------- layer 0 (H=4): h -> hbuf ----------------
  {
    dim3 g(cdiv(N, 64), HF / 64);
    gemm_f32<<<g, blk, 0, stream>>>(h, W0, feat, N, Din, HF);
    scores_kernel<4><<<cdiv(N * 64, 256), blk, 0, stream>>>(feat, al0, ar0, el, er, N);
    init_ms<<<cdiv(N * 4, 256), blk, 0, stream>>>(mu, ssum, N * 4);
    edge_logits<4><<<cdiv(E * 4, 256), blk, 0, stream>>>(src, dst, el, er, ebuf, mu, E);
    edge_exp<4><<<cdiv(E * 4, 256), blk, 0, stream>>>(dst, ebuf, mu, ssum, E);
    init_out<<<cdiv(N * HF, 256), blk, 0, stream>>>(hbuf, b0, N * HF, HF - 1);
    aggregate<4><<<cdiv(E * 64, 256), blk, 0, stream>>>(src, dst, feat, ebuf, ssum, hbuf, E);
  }
  // ---------------- layer 1 (H=4): hbuf -> hbuf ----------------
  {
    dim3 g(cdiv(N, 64), HF / 64);
    gemm_f32<<<g, blk, 0, stream>>>(hbuf, W1, feat, N, HF, HF);
    scores_kernel<4><<<cdiv(N * 64, 256), blk, 0, stream>>>(feat, al1, ar1, el, er, N);
    init_ms<<<cdiv(N * 4, 256), blk, 0, stream>>>(mu, ssum, N * 4);
    edge_logits<4><<<cdiv(E * 4, 256), blk, 0, stream>>>(src, dst, el, er, ebuf, mu, E);
    edge_exp<4><<<cdiv(E * 4, 256), blk, 0, stream>>>(dst, ebuf, mu, ssum, E);
    init_out<<<cdiv(N * HF, 256), blk, 0, stream>>>(hbuf, b1, N * HF, HF - 1);
    aggregate<4><<<cdiv(E * 64, 256), blk, 0, stream>>>(src, dst, feat, ebuf, ssum, hbuf, E);
  }
  // ---------------- layer 2 (H=1): hbuf -> d_out ----------------
  {
    dim3 g(cdiv(N, 64), F2 / 64);
    gemm_f32<<<g, blk, 0, stream>>>(hbuf, W2, feat, N, HF, F2);
    scores_kernel<1><<<cdiv(N * 64, 256), blk, 0, stream>>>(feat, al2, ar2, el, er, N);
    init_ms<<<cdiv(N, 256), blk, 0, stream>>>(mu, ssum, N);
    edge_logits<1><<<cdiv(E, 256), blk, 0, stream>>>(src, dst, el, er, ebuf, mu, E);
    edge_exp<1><<<cdiv(E, 256), blk, 0, stream>>>(dst, ebuf, mu, ssum, E);
    init_out<<<cdiv(N * F2, 256), blk, 0, stream>>>(outp, b2, N * F2, F2 - 1);
    aggregate<1><<<cdiv(E * 64, 256), blk, 0, stream>>>(src, dst, feat, ebuf, ssum, outp, E);
  }
  // ---------------- tail ids ----------------
  copy_ids<<<cdiv(NIDS, 256), blk, 0, stream>>>(ids, outp + (size_t)N * F2, NIDS);
}

// Round 2
// 730.427 us; speedup vs baseline: 2.7469x; 2.7469x over previous
//
#include <hip/hip_runtime.h>
#include <hip/hip_bf16.h>

#define NEG_SLOPE 0.2f

static inline int cdiv(int a, int b) { return (a + b - 1) / b; }

// ---------------- GEMM: C[N,M] = A[N,K] @ B[K,M], f32, 64x64 tile ----------------
__global__ __launch_bounds__(256) void gemm_f32(const float* __restrict__ A,
                                                const float* __restrict__ B,
                                                float* __restrict__ C,
                                                int N, int K, int M) {
  __shared__ float As[16][68];
  __shared__ float Bs[16][64];
  const int tid = threadIdx.x;
  const int row0 = blockIdx.x * 64;
  const int col0 = blockIdx.y * 64;
  const int tx = tid & 15, ty = tid >> 4;
  float acc[4][4] = {};
  for (int k0 = 0; k0 < K; k0 += 16) {
    {
      const int r = tid >> 2, kv = (tid & 3) << 2;
      const int row = row0 + r;
      float4 v = make_float4(0.f, 0.f, 0.f, 0.f);
      if (row < N) v = *reinterpret_cast<const float4*>(&A[(size_t)row * K + k0 + kv]);
      As[kv + 0][r] = v.x; As[kv + 1][r] = v.y; As[kv + 2][r] = v.z; As[kv + 3][r] = v.w;
    }
    {
      const int kr = tid >> 4, cv = (tid & 15) << 2;
      float4 v = *reinterpret_cast<const float4*>(&B[(size_t)(k0 + kr) * M + col0 + cv]);
      *reinterpret_cast<float4*>(&Bs[kr][cv]) = v;
    }
    __syncthreads();
#pragma unroll
    for (int kk = 0; kk < 16; ++kk) {
      float4 av = *reinterpret_cast<const float4*>(&As[kk][ty << 2]);
      float4 bv = *reinterpret_cast<const float4*>(&Bs[kk][tx << 2]);
      const float a[4] = {av.x, av.y, av.z, av.w};
      const float b[4] = {bv.x, bv.y, bv.z, bv.w};
#pragma unroll
      for (int i = 0; i < 4; ++i)
#pragma unroll
        for (int j = 0; j < 4; ++j)
          acc[i][j] = fmaf(a[i], b[j], acc[i][j]);
    }
    __syncthreads();
  }
#pragma unroll
  for (int i = 0; i < 4; ++i) {
    const int row = row0 + (ty << 2) + i;
    if (row < N) {
      float4 v = make_float4(acc[i][0], acc[i][1], acc[i][2], acc[i][3]);
      *reinterpret_cast<float4*>(&C[(size_t)row * M + col0 + (tx << 2)]) = v;
    }
  }
}

// ---------------- per-node attention scores: el/er[N,H] (F==64) ----------------
template <int H>
__global__ void scores_kernel(const float* __restrict__ feat,
                              const float* __restrict__ al,
                              const float* __restrict__ ar,
                              float* __restrict__ el, float* __restrict__ er, int N) {
  const int wid = (int)((blockIdx.x * (size_t)blockDim.x + threadIdx.x) >> 6);
  const int lane = threadIdx.x & 63;
  if (wid >= N) return;
#pragma unroll
  for (int h = 0; h < H; ++h) {
    float v = feat[(size_t)wid * (H * 64) + h * 64 + lane];
    float sl = v * al[h * 64 + lane];
    float sr = v * ar[h * 64 + lane];
#pragma unroll
    for (int off = 32; off; off >>= 1) {
      sl += __shfl_xor(sl, off);
      sr += __shfl_xor(sr, off);
    }
    if (lane == 0) { el[wid * H + h] = sl; er[wid * H + h] = sr; }
  }
}

// ---------------- CSR build ----------------
__global__ void hist_kernel(const int* __restrict__ dst, int* __restrict__ deg, int E) {
  int i = blockIdx.x * blockDim.x + threadIdx.x;
  if (i < E) atomicAdd(&deg[dst[i]], 1);
}

// per-block exclusive scan (256), write block totals
__global__ void scan1(const int* __restrict__ deg, int* __restrict__ offs,
                      int* __restrict__ bsums, int N) {
  __shared__ int tmp[256];
  const int tid = threadIdx.x;
  const int i = blockIdx.x * 256 + tid;
  int v = (i < N) ? deg[i] : 0;
  tmp[tid] = v;
  __syncthreads();
  for (int d = 1; d < 256; d <<= 1) {
    int t = (tid >= d) ? tmp[tid - d] : 0;
    __syncthreads();
    tmp[tid] += t;
    __syncthreads();
  }
  if (i < N) offs[i] = tmp[tid] - v;          // exclusive
  if (tid == 255) bsums[blockIdx.x] = tmp[255];
}

__global__ void scan2(int* __restrict__ bsums, int nb) {
  __shared__ int tmp[256];
  const int tid = threadIdx.x;
  int v = (tid < nb) ? bsums[tid] : 0;
  tmp[tid] = v;
  __syncthreads();
  for (int d = 1; d < 256; d <<= 1) {
    int t = (tid >= d) ? tmp[tid - d] : 0;
    __syncthreads();
    tmp[tid] += t;
    __syncthreads();
  }
  if (tid < nb) bsums[tid] = tmp[tid] - v;    // exclusive block offsets
}

__global__ void scan3(int* __restrict__ offs, const int* __restrict__ bsums, int N, int E) {
  const int i = blockIdx.x * 256 + threadIdx.x;
  if (i < N) offs[i] += bsums[blockIdx.x];
  if (i == 0) offs[N] = E;
}

__global__ void scatter_kernel(const int* __restrict__ src, const int* __restrict__ dst,
                               const int* __restrict__ offs, int* __restrict__ cursor,
                               int* __restrict__ csr_src, int E) {
  int i = blockIdx.x * blockDim.x + threadIdx.x;
  if (i >= E) return;
  int dn = dst[i];
  int pos = atomicAdd(&cursor[dn], 1);
  csr_src[offs[dn] + pos] = src[i];
}

// ---------------- fused edge-softmax + aggregation, one wave per dst node ----------------
template <int H>
__global__ void gat_fused(const int* __restrict__ offs, const int* __restrict__ csr_src,
                          const float* __restrict__ feat, const float* __restrict__ el,
                          const float* __restrict__ er, const float* __restrict__ bias,
                          float* __restrict__ out, int N) {
  const int wid = (int)((blockIdx.x * (size_t)blockDim.x + threadIdx.x) >> 6);
  const int lane = threadIdx.x & 63;
  if (wid >= N) return;
  const int beg = offs[wid], end = offs[wid + 1];
  float erh[H], m[H], s[H], acc[H];
#pragma unroll
  for (int hh = 0; hh < H; ++hh) {
    erh[hh] = er[wid * H + hh];
    m[hh] = -INFINITY; s[hh] = 0.f; acc[hh] = 0.f;
  }
  for (int i = beg; i < end; ++i) {
    const int sn = csr_src[i];
#pragma unroll
    for (int hh = 0; hh < H; ++hh) {
      float e = el[sn * H + hh] + erh[hh];
      e = e > 0.f ? e : NEG_SLOPE * e;
      const float mn = fmaxf(m[hh], e);
      const float sc = __expf(m[hh] - mn);
      const float w = __expf(e - mn);
      const float v = feat[(size_t)sn * (H * 64) + hh * 64 + lane];
      s[hh] = s[hh] * sc + w;
      acc[hh] = acc[hh] * sc + w * v;
      m[hh] = mn;
    }
  }
#pragma unroll
  for (int hh = 0; hh < H; ++hh) {
    float o = acc[hh] / fmaxf(s[hh], 1e-9f) + bias[hh * 64 + lane];
    out[(size_t)wid * (H * 64) + hh * 64 + lane] = o;
  }
}

// ---------------- tail: ids as float ----------------
__global__ void copy_ids(const int* __restrict__ ids, float* __restrict__ out, int n) {
  int i = blockIdx.x * blockDim.x + threadIdx.x;
  if (i < n) out[i] = (float)ids[i];
}

extern "C" void kernel_launch(void* const* d_in, const int* in_sizes, int n_in,
                              void* d_out, int out_size, void* d_ws, size_t ws_size,
                              hipStream_t stream) {
  const float* h   = (const float*)d_in[0];
  const int* src   = (const int*)d_in[1];
  const int* dst   = (const int*)d_in[2];
  const int* ids   = (const int*)d_in[3];
  const float* W0  = (const float*)d_in[4];
  const float* al0 = (const float*)d_in[5];
  const float* ar0 = (const float*)d_in[6];
  const float* b0  = (const float*)d_in[7];
  const float* W1  = (const float*)d_in[8];
  const float* al1 = (const float*)d_in[9];
  const float* ar1 = (const float*)d_in[10];
  const float* b1  = (const float*)d_in[11];
  const float* W2  = (const float*)d_in[12];
  const float* al2 = (const float*)d_in[13];
  const float* ar2 = (const float*)d_in[14];
  const float* b2  = (const float*)d_in[15];

  const int Din = 256, HF = 256, F2 = 64;
  const int N = in_sizes[0] / Din;        // 50000
  const int E = in_sizes[1];              // 800000
  const int NIDS = in_sizes[3];           // 1024

  // workspace layout
  char* p = (char*)d_ws;
  float* feat = (float*)p;            p += (size_t)N * 256 * 4;
  float* hbuf = (float*)p;            p += (size_t)N * 256 * 4;
  float* el   = (float*)p;            p += (size_t)N * 4 * 4;
  float* er   = (float*)p;            p += (size_t)N * 4 * 4;
  int* deg    = (int*)p;              p += (size_t)N * 4;
  int* offs   = (int*)p;              p += (size_t)(N + 1) * 4;
  int* bsums  = (int*)p;              p += 256 * 4;
  int* csr_src = (int*)p;             p += (size_t)E * 4;

  float* outp = (float*)d_out;
  dim3 blk(256);
  const int nb = cdiv(N, 256);

  // ---------------- CSR build (shared by all 3 layers) ----------------
  hipMemsetAsync(deg, 0, (size_t)N * 4, stream);
  hist_kernel<<<cdiv(E, 256), blk, 0, stream>>>(dst, deg, E);
  scan1<<<nb, blk, 0, stream>>>(deg, offs, bsums, N);
  scan2<<<1, blk, 0, stream>>>(bsums, nb);
  scan3<<<nb, blk, 0, stream>>>(offs, bsums, N, E);
  hipMemsetAsync(deg, 0, (size_t)N * 4, stream);  // reuse as cursor
  scatter_kernel<<<cdiv(E, 256), blk, 0, stream>>>(src, dst, offs, deg, csr_src, E);

  // ---------------- layer 0 (H=4): h -> hbuf ----------------
  {
    dim3 g(cdiv(N, 64), HF / 64);
    gemm_f32<<<g, blk, 0, stream>>>(h, W0, feat, N, Din, HF);
    scores_kernel<4><<<cdiv(N * 64, 256), blk, 0, stream>>>(feat, al0, ar0, el, er, N);
    gat_fused<4><<<cdiv(N * 64, 256), blk, 0, stream>>>(offs, csr_src, feat, el, er, b0, hbuf, N);
  }
  // ---------------- layer 1 (H=4): hbuf -> hbuf ----------------
  {
    dim3 g(cdiv(N, 64), HF / 64);
    gemm_f32<<<g, blk, 0, stream>>>(hbuf, W1, feat, N, HF, HF);
    scores_kernel<4><<<cdiv(N * 64, 256), blk, 0, stream>>>(feat, al1, ar1, el, er, N);
    gat_fused<4><<<cdiv(N * 64, 256), blk, 0, stream>>>(offs, csr_src, feat, el, er, b1, hbuf, N);
  }
  // ---------------- layer 2 (H=1): hbuf -> d_out ----------------
  {
    dim3 g(cdiv(N, 64), F2 / 64);
    gemm_f32<<<g, blk, 0, stream>>>(hbuf, W2, feat, N, HF, F2);
    scores_kernel<1><<<cdiv(N * 64, 256), blk, 0, stream>>>(feat, al2, ar2, el, er, N);
    gat_fused<1><<<cdiv(N * 64, 256), blk, 0, stream>>>(offs, csr_src, feat, el, er, b2, outp, N);
  }
  // ---------------- tail ids ----------------
  copy_ids<<<cdiv(NIDS, 256), blk, 0, stream>>>(ids, outp + (size_t)N * F2, NIDS);
}

// Round 3
// 626.344 us; speedup vs baseline: 3.2034x; 1.1662x over previous
//
#include <hip/hip_runtime.h>
#include <hip/hip_bf16.h>

#define NEG_SLOPE 0.2f

typedef __attribute__((ext_vector_type(8))) short bf16x8;
typedef __attribute__((ext_vector_type(4))) float f32x4;

static inline int cdiv(int a, int b) { return (a + b - 1) / b; }

__device__ inline unsigned short f2bf(float x) {
  __hip_bfloat16 b = __float2bfloat16(x);
  return *reinterpret_cast<unsigned short*>(&b);
}
__device__ inline float bf2f(unsigned short u) {
  __hip_bfloat16 b = *reinterpret_cast<__hip_bfloat16*>(&u);
  return __bfloat162float(b);
}

// ---------------- split f32 -> bf16 hi/lo ----------------
__global__ void split_kernel(const float* __restrict__ x, unsigned short* __restrict__ hi,
                             unsigned short* __restrict__ lo, int n4) {
  int i = blockIdx.x * blockDim.x + threadIdx.x;
  if (i >= n4) return;
  float4 v = reinterpret_cast<const float4*>(x)[i];
  unsigned short h0 = f2bf(v.x), h1 = f2bf(v.y), h2 = f2bf(v.z), h3 = f2bf(v.w);
  ushort4 hv; hv.x = h0; hv.y = h1; hv.z = h2; hv.w = h3;
  ushort4 lv;
  lv.x = f2bf(v.x - bf2f(h0)); lv.y = f2bf(v.y - bf2f(h1));
  lv.z = f2bf(v.z - bf2f(h2)); lv.w = f2bf(v.w - bf2f(h3));
  reinterpret_cast<ushort4*>(hi)[i] = hv;
  reinterpret_cast<ushort4*>(lo)[i] = lv;
}

// ---------------- split + transpose W[K][Mo] -> T[Mo][K] bf16 hi/lo ----------------
__global__ void splitT_kernel(const float* __restrict__ W, unsigned short* __restrict__ hi,
                              unsigned short* __restrict__ lo, int K, int Mo) {
  int i = blockIdx.x * blockDim.x + threadIdx.x;
  if (i >= K * Mo) return;
  int k = i / Mo, m = i - k * Mo;
  float v = W[i];
  unsigned short h = f2bf(v);
  hi[(size_t)m * K + k] = h;
  lo[(size_t)m * K + k] = f2bf(v - bf2f(h));
}

// ---------------- GEMM: C[M][Ncols] = (Ahi+Alo)[M][K] @ (BThi+BTlo)[Ncols][K]^T ----------------
// 3-MFMA split emulation, fp32-comparable accuracy. BM=128, BN=NF*32, BK=32, 4 waves (2x2).
template <int NF>
__global__ __launch_bounds__(256) void gemm_split(
    const unsigned short* __restrict__ Ahi, const unsigned short* __restrict__ Alo,
    const unsigned short* __restrict__ BThi, const unsigned short* __restrict__ BTlo,
    float* __restrict__ C, int M, int K, int Ncols) {
  constexpr int BN = NF * 32;
  // stride 88 elems = 176B: 16B-aligned vector ops, rows r/r+8 alias only (2-way, free)
  __shared__ unsigned short As[128][88];   // hi at [0,32), lo at [48,80)
  __shared__ unsigned short Bs[BN][88];
  const int tid = threadIdx.x;
  const int row0 = blockIdx.x * 128;
  const int col0 = blockIdx.y * BN;
  const int wid = tid >> 6, lane = tid & 63;
  const int wm = wid >> 1, wn = wid & 1;
  const int l15 = lane & 15, lg = lane >> 4;
  f32x4 acc[4][NF];
#pragma unroll
  for (int m = 0; m < 4; ++m)
#pragma unroll
    for (int n = 0; n < NF; ++n) acc[m][n] = (f32x4){0.f, 0.f, 0.f, 0.f};

  const uint4 zero4 = {0u, 0u, 0u, 0u};
  for (int k0 = 0; k0 < K; k0 += 32) {
    {  // stage A: 128 rows x 4 kgroups, 2 iters
      int r = tid >> 2;
      const int kg = tid & 3;
#pragma unroll
      for (int it = 0; it < 2; ++it, r += 64) {
        const int grow = row0 + r;
        uint4 vh = zero4, vl = zero4;
        if (grow < M) {
          vh = *reinterpret_cast<const uint4*>(&Ahi[(size_t)grow * K + k0 + kg * 8]);
          vl = *reinterpret_cast<const uint4*>(&Alo[(size_t)grow * K + k0 + kg * 8]);
        }
        *reinterpret_cast<uint4*>(&As[r][kg * 8]) = vh;
        *reinterpret_cast<uint4*>(&As[r][48 + kg * 8]) = vl;
      }
    }
    {  // stage B: BN rows x 4 kgroups
      int r = tid >> 2;
      const int kg = tid & 3;
#pragma unroll
      for (int it = 0; it < BN / 64; ++it, r += 64) {
        const int gcol = col0 + r;
        uint4 vh = *reinterpret_cast<const uint4*>(&BThi[(size_t)gcol * K + k0 + kg * 8]);
        uint4 vl = *reinterpret_cast<const uint4*>(&BTlo[(size_t)gcol * K + k0 + kg * 8]);
        *reinterpret_cast<uint4*>(&Bs[r][kg * 8]) = vh;
        *reinterpret_cast<uint4*>(&Bs[r][48 + kg * 8]) = vl;
      }
    }
    __syncthreads();
    bf16x8 ah[4], al[4];
#pragma unroll
    for (int m = 0; m < 4; ++m) {
      const int row = wm * 64 + m * 16 + l15;
      ah[m] = *reinterpret_cast<const bf16x8*>(&As[row][lg * 8]);
      al[m] = *reinterpret_cast<const bf16x8*>(&As[row][48 + lg * 8]);
    }
#pragma unroll
    for (int n = 0; n < NF; ++n) {
      const int col = wn * (NF * 16) + n * 16 + l15;
      bf16x8 bh = *reinterpret_cast<const bf16x8*>(&Bs[col][lg * 8]);
      bf16x8 bl = *reinterpret_cast<const bf16x8*>(&Bs[col][48 + lg * 8]);
#pragma unroll
      for (int m = 0; m < 4; ++m) {
        acc[m][n] = __builtin_amdgcn_mfma_f32_16x16x32_bf16(ah[m], bh, acc[m][n], 0, 0, 0);
        acc[m][n] = __builtin_amdgcn_mfma_f32_16x16x32_bf16(ah[m], bl, acc[m][n], 0, 0, 0);
        acc[m][n] = __builtin_amdgcn_mfma_f32_16x16x32_bf16(al[m], bh, acc[m][n], 0, 0, 0);
      }
    }
    __syncthreads();
  }
  // epilogue: C/D layout col=lane&15, row=(lane>>4)*4+j (m89-verified)
#pragma unroll
  for (int m = 0; m < 4; ++m) {
#pragma unroll
    for (int n = 0; n < NF; ++n) {
      const int col = col0 + wn * (NF * 16) + n * 16 + l15;
#pragma unroll
      for (int j = 0; j < 4; ++j) {
        const int row = row0 + wm * 64 + m * 16 + lg * 4 + j;
        if (row < M) C[(size_t)row * Ncols + col] = acc[m][n][j];
      }
    }
  }
}

// ---------------- per-node attention scores: el/er[N,H] (F==64) ----------------
template <int H>
__global__ void scores_kernel(const float* __restrict__ feat,
                              const float* __restrict__ al,
                              const float* __restrict__ ar,
                              float* __restrict__ el, float* __restrict__ er, int N) {
  const int wid = (int)((blockIdx.x * (size_t)blockDim.x + threadIdx.x) >> 6);
  const int lane = threadIdx.x & 63;
  if (wid >= N) return;
#pragma unroll
  for (int h = 0; h < H; ++h) {
    float v = feat[(size_t)wid * (H * 64) + h * 64 + lane];
    float sl = v * al[h * 64 + lane];
    float sr = v * ar[h * 64 + lane];
#pragma unroll
    for (int off = 32; off; off >>= 1) {
      sl += __shfl_xor(sl, off);
      sr += __shfl_xor(sr, off);
    }
    if (lane == 0) { el[wid * H + h] = sl; er[wid * H + h] = sr; }
  }
}

// ---------------- CSR build ----------------
__global__ void hist_kernel(const int* __restrict__ dst, int* __restrict__ deg, int E) {
  int i = blockIdx.x * blockDim.x + threadIdx.x;
  if (i < E) atomicAdd(&deg[dst[i]], 1);
}

__global__ void scan1(const int* __restrict__ deg, int* __restrict__ offs,
                      int* __restrict__ bsums, int N) {
  __shared__ int tmp[256];
  const int tid = threadIdx.x;
  const int i = blockIdx.x * 256 + tid;
  int v = (i < N) ? deg[i] : 0;
  tmp[tid] = v;
  __syncthreads();
  for (int d = 1; d < 256; d <<= 1) {
    int t = (tid >= d) ? tmp[tid - d] : 0;
    __syncthreads();
    tmp[tid] += t;
    __syncthreads();
  }
  if (i < N) offs[i] = tmp[tid] - v;
  if (tid == 255) bsums[blockIdx.x] = tmp[255];
}

__global__ void scan2(int* __restrict__ bsums, int nb) {
  __shared__ int tmp[256];
  const int tid = threadIdx.x;
  int v = (tid < nb) ? bsums[tid] : 0;
  tmp[tid] = v;
  __syncthreads();
  for (int d = 1; d < 256; d <<= 1) {
    int t = (tid >= d) ? tmp[tid - d] : 0;
    __syncthreads();
    tmp[tid] += t;
    __syncthreads();
  }
  if (tid < nb) bsums[tid] = tmp[tid] - v;
}

__global__ void scan3(int* __restrict__ offs, const int* __restrict__ bsums, int N, int E) {
  const int i = blockIdx.x * 256 + threadIdx.x;
  if (i < N) offs[i] += bsums[blockIdx.x];
  if (i == 0) offs[N] = E;
}

__global__ void scatter_kernel(const int* __restrict__ src, const int* __restrict__ dst,
                               const int* __restrict__ offs, int* __restrict__ cursor,
                               int* __restrict__ csr_src, int E) {
  int i = blockIdx.x * blockDim.x + threadIdx.x;
  if (i >= E) return;
  int dn = dst[i];
  int pos = atomicAdd(&cursor[dn], 1);
  csr_src[offs[dn] + pos] = src[i];
}

// ---------------- pass 1: per-node softmax stats + normalized alpha per edge ----------------
// one wave per dst node, lanes parallel over incoming edges
template <int H>
__global__ void alpha_kernel(const int* __restrict__ offs, const int* __restrict__ csr_src,
                             const float* __restrict__ el, const float* __restrict__ er,
                             float* __restrict__ abuf, int N) {
  const int wid = (int)((blockIdx.x * (size_t)blockDim.x + threadIdx.x) >> 6);
  const int lane = threadIdx.x & 63;
  if (wid >= N) return;
  const int beg = offs[wid], end = offs[wid + 1];
  if (beg >= end) return;
  float erh[H], m[H], s[H];
#pragma unroll
  for (int h = 0; h < H; ++h) { erh[h] = er[wid * H + h]; m[h] = -INFINITY; s[h] = 0.f; }
  for (int i0 = beg; i0 < end; i0 += 64) {
    const int i = i0 + lane;
    const bool valid = i < end;
    const int sn = valid ? csr_src[i] : 0;
    float e[H];
    if constexpr (H == 4) {
      float4 v = *reinterpret_cast<const float4*>(&el[(size_t)sn * 4]);
      e[0] = v.x + erh[0]; e[1] = v.y + erh[1]; e[2] = v.z + erh[2]; e[3] = v.w + erh[3];
    } else {
      e[0] = el[sn] + erh[0];
    }
#pragma unroll
    for (int h = 0; h < H; ++h) {
      e[h] = e[h] > 0.f ? e[h] : NEG_SLOPE * e[h];
      if (!valid) e[h] = -INFINITY;
      float cm = e[h];
#pragma unroll
      for (int off = 32; off; off >>= 1) cm = fmaxf(cm, __shfl_xor(cm, off));
      const float nm = fmaxf(m[h], cm);
      float cs = __expf(e[h] - nm);   // exp(-inf)=0 for invalid lanes
#pragma unroll
      for (int off = 32; off; off >>= 1) cs += __shfl_xor(cs, off);
      s[h] = s[h] * __expf(m[h] - nm) + cs;
      m[h] = nm;
    }
  }
  float inv[H];
#pragma unroll
  for (int h = 0; h < H; ++h) inv[h] = 1.f / fmaxf(s[h], 1e-9f);
  for (int i0 = beg; i0 < end; i0 += 64) {
    const int i = i0 + lane;
    if (i >= end) break;
    const int sn = csr_src[i];
    float e[H];
    if constexpr (H == 4) {
      float4 v = *reinterpret_cast<const float4*>(&el[(size_t)sn * 4]);
      e[0] = v.x + erh[0]; e[1] = v.y + erh[1]; e[2] = v.z + erh[2]; e[3] = v.w + erh[3];
    } else {
      e[0] = el[sn] + erh[0];
    }
#pragma unroll
    for (int h = 0; h < H; ++h) {
      e[h] = e[h] > 0.f ? e[h] : NEG_SLOPE * e[h];
      e[h] = __expf(e[h] - m[h]) * inv[h];
    }
    if constexpr (H == 4) {
      float4 o; o.x = e[0]; o.y = e[1]; o.z = e[2]; o.w = e[3];
      *reinterpret_cast<float4*>(&abuf[(size_t)i * 4]) = o;
    } else {
      abuf[i] = e[0];
    }
  }
}

// ---------------- pass 2: out[dst] = sum alpha*feat[src] + bias; optional bf16 hi/lo split out ----------------
template <int H, bool SPLIT>
__global__ void aggregate2(const int* __restrict__ offs, const int* __restrict__ csr_src,
                           const float* __restrict__ feat, const float* __restrict__ abuf,
                           const float* __restrict__ bias, float* __restrict__ outf,
                           unsigned short* __restrict__ outhi, unsigned short* __restrict__ outlo,
                           int N) {
  const int wid = (int)((blockIdx.x * (size_t)blockDim.x + threadIdx.x) >> 6);
  const int lane = threadIdx.x & 63;
  if (wid >= N) return;
  const int beg = offs[wid], end = offs[wid + 1];
  float acc[H];
#pragma unroll
  for (int h = 0; h < H; ++h) acc[h] = 0.f;
  int i = beg;
  for (; i + 1 < end; i += 2) {
    const int sn0 = csr_src[i], sn1 = csr_src[i + 1];
    if constexpr (H == 4) {
      float4 a0 = *reinterpret_cast<const float4*>(&abuf[(size_t)i * 4]);
      float4 a1 = *reinterpret_cast<const float4*>(&abuf[(size_t)(i + 1) * 4]);
      const float* f0 = &feat[(size_t)sn0 * 256 + lane];
      const float* f1 = &feat[(size_t)sn1 * 256 + lane];
      float v00 = f0[0], v01 = f0[64], v02 = f0[128], v03 = f0[192];
      float v10 = f1[0], v11 = f1[64], v12 = f1[128], v13 = f1[192];
      acc[0] += a0.x * v00 + a1.x * v10;
      acc[1] += a0.y * v01 + a1.y * v11;
      acc[2] += a0.z * v02 + a1.z * v12;
      acc[3] += a0.w * v03 + a1.w * v13;
    } else {
      float a0 = abuf[i], a1 = abuf[i + 1];
      acc[0] += a0 * feat[(size_t)sn0 * 64 + lane] + a1 * feat[(size_t)sn1 * 64 + lane];
    }
  }
  if (i < end) {
    const int sn = csr_src[i];
    if constexpr (H == 4) {
      float4 a = *reinterpret_cast<const float4*>(&abuf[(size_t)i * 4]);
      const float* f = &feat[(size_t)sn * 256 + lane];
      acc[0] += a.x * f[0]; acc[1] += a.y * f[64];
      acc[2] += a.z * f[128]; acc[3] += a.w * f[192];
    } else {
      acc[0] += abuf[i] * feat[(size_t)sn * 64 + lane];
    }
  }
#pragma unroll
  for (int h = 0; h < H; ++h) {
    const float o = acc[h] + bias[h * 64 + lane];
    const size_t idx = (size_t)wid * (H * 64) + h * 64 + lane;
    if constexpr (SPLIT) {
      unsigned short hb = f2bf(o);
      outhi[idx] = hb;
      outlo[idx] = f2bf(o - bf2f(hb));
    } else {
      outf[idx] = o;
    }
  }
}

// ---------------- tail: ids as float ----------------
__global__ void copy_ids(const int* __restrict__ ids, float* __restrict__ out, int n) {
  int i = blockIdx.x * blockDim.x + threadIdx.x;
  if (i < n) out[i] = (float)ids[i];
}

extern "C" void kernel_launch(void* const* d_in, const int* in_sizes, int n_in,
                              void* d_out, int out_size, void* d_ws, size_t ws_size,
                              hipStream_t stream) {
  const float* h   = (const float*)d_in[0];
  const int* src   = (const int*)d_in[1];
  const int* dst   = (const int*)d_in[2];
  const int* ids   = (const int*)d_in[3];
  const float* W0  = (const float*)d_in[4];
  const float* al0 = (const float*)d_in[5];
  const float* ar0 = (const float*)d_in[6];
  const float* b0  = (const float*)d_in[7];
  const float* W1  = (const float*)d_in[8];
  const float* al1 = (const float*)d_in[9];
  const float* ar1 = (const float*)d_in[10];
  const float* b1  = (const float*)d_in[11];
  const float* W2  = (const float*)d_in[12];
  const float* al2 = (const float*)d_in[13];
  const float* ar2 = (const float*)d_in[14];
  const float* b2  = (const float*)d_in[15];

  const int Din = 256, HF = 256, F2 = 64;
  const int N = in_sizes[0] / Din;        // 50000
  const int E = in_sizes[1];              // 800000
  const int NIDS = in_sizes[3];           // 1024

  // workspace layout (16B-aligned chunks)
  char* p = (char*)d_ws;
  float* feat = (float*)p;             p += (size_t)N * 256 * 4;       // 51.2 MB
  unsigned short* Ahi = (unsigned short*)p; p += (size_t)N * 256 * 2;  // 25.6 MB
  unsigned short* Alo = (unsigned short*)p; p += (size_t)N * 256 * 2;  // 25.6 MB
  unsigned short* W0hi = (unsigned short*)p; p += (size_t)HF * Din * 2;
  unsigned short* W0lo = (unsigned short*)p; p += (size_t)HF * Din * 2;
  unsigned short* W1hi = (unsigned short*)p; p += (size_t)HF * HF * 2;
  unsigned short* W1lo = (unsigned short*)p; p += (size_t)HF * HF * 2;
  unsigned short* W2hi = (unsigned short*)p; p += (size_t)F2 * HF * 2;
  unsigned short* W2lo = (unsigned short*)p; p += (size_t)F2 * HF * 2;
  float* el   = (float*)p;             p += (size_t)N * 4 * 4;
  float* er   = (float*)p;             p += (size_t)N * 4 * 4;
  float* abuf = (float*)p;             p += (size_t)E * 4 * 4;         // 12.8 MB
  int* deg    = (int*)p;               p += (size_t)N * 4;
  int* offs   = (int*)p;               p += (size_t)(N + 16) * 4;
  int* bsums  = (int*)p;               p += 256 * 4;
  int* csr_src = (int*)p;              p += (size_t)E * 4;

  float* outp = (float*)d_out;
  dim3 blk(256);
  const int nb = cdiv(N, 256);

  // ---------------- pre-passes: splits ----------------
  split_kernel<<<cdiv(N * 256 / 4, 256), blk, 0, stream>>>(h, Ahi, Alo, N * 256 / 4);
  splitT_kernel<<<cdiv(Din * HF, 256), blk, 0, stream>>>(W0, W0hi, W0lo, Din, HF);
  splitT_kernel<<<cdiv(HF * HF, 256), blk, 0, stream>>>(W1, W1hi, W1lo, HF, HF);
  splitT_kernel<<<cdiv(HF * F2, 256), blk, 0, stream>>>(W2, W2hi, W2lo, HF, F2);

  // ---------------- CSR build (shared by all 3 layers) ----------------
  hipMemsetAsync(deg, 0, (size_t)N * 4, stream);
  hist_kernel<<<cdiv(E, 256), blk, 0, stream>>>(dst, deg, E);
  scan1<<<nb, blk, 0, stream>>>(deg, offs, bsums, N);
  scan2<<<1, blk, 0, stream>>>(bsums, nb);
  scan3<<<nb, blk, 0, stream>>>(offs, bsums, N, E);
  hipMemsetAsync(deg, 0, (size_t)N * 4, stream);
  scatter_kernel<<<cdiv(E, 256), blk, 0, stream>>>(src, dst, offs, deg, csr_src, E);

  // ---------------- layer 0 (H=4): (Ahi,Alo) -> feat -> (Ahi,Alo) ----------------
  {
    dim3 g(cdiv(N, 128), HF / 128);
    gemm_split<4><<<g, blk, 0, stream>>>(Ahi, Alo, W0hi, W0lo, feat, N, Din, HF);
    scores_kernel<4><<<cdiv(N * 64, 256), blk, 0, stream>>>(feat, al0, ar0, el, er, N);
    alpha_kernel<4><<<cdiv(N * 64, 256), blk, 0, stream>>>(offs, csr_src, el, er, abuf, N);
    aggregate2<4, true><<<cdiv(N * 64, 256), blk, 0, stream>>>(offs, csr_src, feat, abuf, b0,
                                                               nullptr, Ahi, Alo, N);
  }
  // ---------------- layer 1 (H=4) ----------------
  {
    dim3 g(cdiv(N, 128), HF / 128);
    gemm_split<4><<<g, blk, 0, stream>>>(Ahi, Alo, W1hi, W1lo, feat, N, HF, HF);
    scores_kernel<4><<<cdiv(N * 64, 256), blk, 0, stream>>>(feat, al1, ar1, el, er, N);
    alpha_kernel<4><<<cdiv(N * 64, 256), blk, 0, stream>>>(offs, csr_src, el, er, abuf, N);
    aggregate2<4, true><<<cdiv(N * 64, 256), blk, 0, stream>>>(offs, csr_src, feat, abuf, b1,
                                                               nullptr, Ahi, Alo, N);
  }
  // ---------------- layer 2 (H=1): -> d_out ----------------
  {
    dim3 g(cdiv(N, 128), 1);
    gemm_split<2><<<g, blk, 0, stream>>>(Ahi, Alo, W2hi, W2lo, feat, N, HF, F2);
    scores_kernel<1><<<cdiv(N * 64, 256), blk, 0, stream>>>(feat, al2, ar2, el, er, N);
    alpha_kernel<1><<<cdiv(N * 64, 256), blk, 0, stream>>>(offs, csr_src, el, er, abuf, N);
    aggregate2<1, false><<<cdiv(N * 64, 256), blk, 0, stream>>>(offs, csr_src, feat, abuf, b2,
                                                                outp, nullptr, nullptr, N);
  }
  // ---------------- tail ids ----------------
  copy_ids<<<cdiv(NIDS, 256), blk, 0, stream>>>(ids, outp + (size_t)N * F2, NIDS);
}